// Round 4
// baseline (987.421 us; speedup 1.0000x reference)
//
#include <hip/hip_runtime.h>
#include <hip/hip_bf16.h>

#define N0 4096
#define N1 16384
#define HID 128
#define LAT 64
#define DIM 3
#define NAUG 21
#define JTOT 512   // xl(128) | xr(128) | lins(128) | pe(128)
#define KP 132     // padded k (131 real + 1 zero row)

__device__ __constant__ int c_aug[NAUG] = {1,2,3,4,5,6,7,8,9,10,11,12,13,14,
                                           15,16,17,18,19,21,24};

// ---------------------------------------------------------------------------
// Prep: transpose/concat weights into Wt[c][k(132, padded)][j(512)],
// bias_cat[c][512], and lin0 weight transpose Wt0[k(64)][j(128)].
// ---------------------------------------------------------------------------
__global__ void prep_kernel(const float* __restrict__ Wl,
                            const float* __restrict__ Wr,
                            const float* __restrict__ We,
                            const float* __restrict__ linsW,
                            const float* __restrict__ bl,
                            const float* __restrict__ br,
                            const float* __restrict__ linsb,
                            const float* __restrict__ lin0W,
                            float* __restrict__ Wt,
                            float* __restrict__ bias_cat,
                            float* __restrict__ Wt0) {
    int tid = blockIdx.x * blockDim.x + threadIdx.x;
    const int NWT = 4 * KP * JTOT;           // 270336
    if (tid < NWT) {
        int c = tid / (KP * JTOT);
        int rem = tid - c * KP * JTOT;
        int k = rem / JTOT;
        int j = rem - k * JTOT;
        float v = 0.0f;
        if (k < 131) {
            if (j < 128)        v = Wl[(c * 128 + j) * 131 + k];
            else if (j < 256)   v = Wr[(c * 128 + (j - 128)) * 131 + k];
            else if (j < 384)   v = linsW[(c * 128 + (j - 256)) * 131 + k];
            else                v = (k >= 128) ? We[(c * 128 + (j - 384)) * 3 + (k - 128)]
                                               : 0.0f;
        }
        Wt[tid] = v;
    } else if (tid < NWT + 4 * JTOT) {       // bias_cat
        int idx = tid - NWT;
        int c = idx / JTOT;
        int j = idx - c * JTOT;
        float v;
        if (j < 128)        v = bl[c * 128 + j];
        else if (j < 256)   v = br[c * 128 + (j - 128)];
        else if (j < 384)   v = linsb[c * 128 + (j - 256)];
        else                v = 0.0f;
        bias_cat[idx] = v;
    } else if (tid < NWT + 4 * JTOT + 64 * 128) {  // Wt0
        int idx = tid - NWT - 4 * JTOT;
        int k = idx / 128;
        int j = idx - k * 128;
        Wt0[idx] = lin0W[j * 64 + k];
    }
}

// ---------------------------------------------------------------------------
// lin0: x0[n][j] = latent[n] . lin0_W[j] + b[j]   (4096x64 @ 64x128)
// ---------------------------------------------------------------------------
__global__ void lin0_kernel(const float* __restrict__ latent,
                            const float* __restrict__ Wt0,
                            const float* __restrict__ b,
                            float* __restrict__ x0) {
    __shared__ float lrow[64];
    int n = blockIdx.x;
    int j = threadIdx.x;
    if (j < 64) lrow[j] = latent[n * 64 + j];
    __syncthreads();
    float acc = b[j];
#pragma unroll 8
    for (int k = 0; k < 64; ++k) acc += lrow[k] * Wt0[k * 128 + j];
    x0[n * 128 + j] = acc;
}

// ---------------------------------------------------------------------------
// Fused per-layer GEMM with register double-buffer prefetch of W.
// Per 4-k chunk: prefetch next chunk's 8 float4 W loads (no consumer this
// iter -> vmcnt deferred across 128 FMAs), compute on current buffer.
// ---------------------------------------------------------------------------
#define GR 16   // rows per block
__global__ __launch_bounds__(256)
void fused_gemm_kernel(const float* __restrict__ x,
                       const float* __restrict__ pos,
                       const float* __restrict__ Wt,       // [132][512] this layer
                       const float* __restrict__ bias_cat, // [512] this layer
                       float* __restrict__ xl, float* __restrict__ xr,
                       float* __restrict__ lin, float* __restrict__ pe,
                       int N) {
    __shared__ float h[GR][KP];
    int n0 = blockIdx.x * GR;
    int tid = threadIdx.x;
    for (int idx = tid; idx < GR * KP; idx += 256) {
        int r = idx / KP;
        int k = idx - r * KP;
        float v;
        if (k < 128)      v = x[(n0 + r) * 128 + k];
        else if (k < 131) v = pos[(n0 + r) * 3 + (k - 128)];
        else              v = 0.0f;
        h[r][k] = v;
    }
    __syncthreads();

    int jg = tid & 63;
    int rg = tid >> 6;
    int j0 = jg * 8;
    int r0 = rg * 4;

    float acc[4][8];
    {
        float bv[8];
        *(float4*)&bv[0] = *(const float4*)&bias_cat[j0];
        *(float4*)&bv[4] = *(const float4*)&bias_cat[j0 + 4];
#pragma unroll
        for (int r = 0; r < 4; ++r)
#pragma unroll
            for (int c = 0; c < 8; ++c) acc[r][c] = bv[c];
    }

    float wv[2][4][8];
#pragma unroll
    for (int kk = 0; kk < 4; ++kk) {
        *(float4*)&wv[0][kk][0] = *(const float4*)&Wt[kk * JTOT + j0];
        *(float4*)&wv[0][kk][4] = *(const float4*)&Wt[kk * JTOT + j0 + 4];
    }

    int buf = 0;
    for (int k = 0; k < KP; k += 4) {
        if (k + 4 < KP) {
#pragma unroll
            for (int kk = 0; kk < 4; ++kk) {
                *(float4*)&wv[buf ^ 1][kk][0] = *(const float4*)&Wt[(k + 4 + kk) * JTOT + j0];
                *(float4*)&wv[buf ^ 1][kk][4] = *(const float4*)&Wt[(k + 4 + kk) * JTOT + j0 + 4];
            }
        }
        float ha[4][4];
#pragma unroll
        for (int r = 0; r < 4; ++r)
            *(float4*)&ha[r][0] = *(const float4*)&h[r0 + r][k];
#pragma unroll
        for (int kk = 0; kk < 4; ++kk)
#pragma unroll
            for (int r = 0; r < 4; ++r)
#pragma unroll
                for (int c = 0; c < 8; ++c)
                    acc[r][c] += ha[r][kk] * wv[buf][kk][c];
        buf ^= 1;
    }

    int seg = j0 >> 7;          // 0..3
    int jj = j0 & 127;
    float* dst = (seg == 0) ? xl : (seg == 1) ? xr : (seg == 2) ? lin : pe;
#pragma unroll
    for (int r = 0; r < 4; ++r) {
        float* p = &dst[(size_t)(n0 + r0 + r) * 128 + jj];
        *(float4*)p       = make_float4(acc[r][0], acc[r][1], acc[r][2], acc[r][3]);
        *(float4*)(p + 4) = make_float4(acc[r][4], acc[r][5], acc[r][6], acc[r][7]);
    }
}

// ---------------------------------------------------------------------------
// GATv2 gather v2: compute all 22 per-lane partial dots first, THEN do the
// 6 butterfly rounds batched over all 22 values (independent shuffles ->
// throughput-bound, not a 6-deep dependent chain per edge).
// ---------------------------------------------------------------------------
__global__ __launch_bounds__(256)
void gat_gather_kernel(const float* __restrict__ xl, const float* __restrict__ xr,
                       const float* __restrict__ pe, const float* __restrict__ lin,
                       const float* __restrict__ att, const float* __restrict__ bias,
                       float* __restrict__ xout, int N) {
    int wave = threadIdx.x >> 6;
    int lane = threadIdx.x & 63;
    int d = blockIdx.x * 4 + wave;
    if (d >= N) return;
    int i0 = 2 * lane;

    float att0 = att[i0], att1 = att[i0 + 1];
    float2 xld = *(const float2*)&xl[d * 128 + i0];
    float2 xrd = *(const float2*)&xr[d * 128 + i0];
    float2 ped = *(const float2*)&pe[d * 128 + i0];

    float a[NAUG + 1];
    float xs0[NAUG], xs1[NAUG];
    float pes0 = 0.0f, pes1 = 0.0f;

    // phase 1: per-lane partial attention dots (no cross-lane ops)
#pragma unroll
    for (int k = 0; k < NAUG; ++k) {
        int s = d - c_aug[k];
        if (s < 0) s += N;
        float2 xls = *(const float2*)&xl[s * 128 + i0];
        float2 pes = *(const float2*)&pe[s * 128 + i0];
        xs0[k] = xls.x; xs1[k] = xls.y;
        pes0 += pes.x;  pes1 += pes.y;
        float m0 = xls.x + xrd.x + ped.x - pes.x;
        float m1 = xls.y + xrd.y + ped.y - pes.y;
        m0 = m0 > 0.0f ? m0 : 0.2f * m0;
        m1 = m1 > 0.0f ? m1 : 0.2f * m1;
        a[k] = att0 * m0 + att1 * m1;
    }
    {   // self loop: eattr = mean over in-edges = ped - mean(pes)
        const float inv21 = 1.0f / 21.0f;
        float m0 = xld.x + xrd.x + (ped.x - pes0 * inv21);
        float m1 = xld.y + xrd.y + (ped.y - pes1 * inv21);
        m0 = m0 > 0.0f ? m0 : 0.2f * m0;
        m1 = m1 > 0.0f ? m1 : 0.2f * m1;
        a[NAUG] = att0 * m0 + att1 * m1;
    }

    // phase 2: batched butterfly reduction of all 22 partials
#pragma unroll
    for (int off = 1; off < 64; off <<= 1) {
#pragma unroll
        for (int k = 0; k <= NAUG; ++k)
            a[k] += __shfl_xor(a[k], off, 64);
    }

    // phase 3: softmax + weighted aggregate + elu + residual
    float amax = a[0];
#pragma unroll
    for (int k = 1; k <= NAUG; ++k) amax = fmaxf(amax, a[k]);
    float den = 0.0f;
#pragma unroll
    for (int k = 0; k <= NAUG; ++k) { a[k] = __expf(a[k] - amax); den += a[k]; }
    float inv = 1.0f / (den + 1e-16f);

    float o0 = 0.0f, o1 = 0.0f;
#pragma unroll
    for (int k = 0; k < NAUG; ++k) {
        float al = a[k] * inv;
        o0 += al * xs0[k];
        o1 += al * xs1[k];
    }
    {
        float al = a[NAUG] * inv;
        o0 += al * xld.x;
        o1 += al * xld.y;
    }
    o0 += bias[i0];
    o1 += bias[i0 + 1];
    o0 = o0 > 0.0f ? o0 : __expf(o0) - 1.0f;
    o1 = o1 > 0.0f ? o1 : __expf(o1) - 1.0f;
    float2 l2 = *(const float2*)&lin[d * 128 + i0];
    float2 res;
    res.x = o0 + l2.x;
    res.y = o1 + l2.y;
    *(float2*)&xout[d * 128 + i0] = res;
}

// ---------------------------------------------------------------------------
// knn: float4-padded LDS points, 4 y per thread, 32 chunks of 128 points.
// ---------------------------------------------------------------------------
#define KCH 32
#define KCS 128   // 4096 / 32
#define YPT 4

__device__ __forceinline__ void top3_insert(float d2, int gi,
                                            float (&bd)[3], int (&bi)[3]) {
    if (d2 < bd[2]) {
        if (d2 < bd[0])      { bd[2]=bd[1]; bi[2]=bi[1]; bd[1]=bd[0]; bi[1]=bi[0]; bd[0]=d2; bi[0]=gi; }
        else if (d2 < bd[1]) { bd[2]=bd[1]; bi[2]=bi[1]; bd[1]=d2;    bi[1]=gi; }
        else                 { bd[2]=d2;    bi[2]=gi; }
    }
}

__global__ __launch_bounds__(256)
void knn_part_kernel(const float* __restrict__ pos0, const float* __restrict__ pos1,
                     float* __restrict__ pb_d, int* __restrict__ pb_i) {
    __shared__ float4 sx[KCS];
    int tid = threadIdx.x;
    int chunk = blockIdx.y;
    for (int t = tid; t < KCS; t += 256) {
        const float* p = &pos0[(chunk * KCS + t) * 3];
        sx[t] = make_float4(p[0], p[1], p[2], 0.0f);
    }
    __syncthreads();
    int ybase = blockIdx.x * (256 * YPT) + tid;
    float py[YPT][3];
#pragma unroll
    for (int u = 0; u < YPT; ++u) {
        int y = ybase + u * 256;
        py[u][0] = pos1[y * 3];
        py[u][1] = pos1[y * 3 + 1];
        py[u][2] = pos1[y * 3 + 2];
    }
    float bd[YPT][3]; int bi[YPT][3];
#pragma unroll
    for (int u = 0; u < YPT; ++u) {
        bd[u][0] = bd[u][1] = bd[u][2] = 1e30f;
        bi[u][0] = bi[u][1] = bi[u][2] = 0;
    }
    int gbase = chunk * KCS;
    for (int i = 0; i < KCS; i += 4) {
        float4 s[4];
#pragma unroll
        for (int v = 0; v < 4; ++v) s[v] = sx[i + v];
#pragma unroll
        for (int v = 0; v < 4; ++v) {
            int gi = gbase + i + v;
#pragma unroll
            for (int u = 0; u < YPT; ++u) {
                float dx = py[u][0] - s[v].x;
                float dy = py[u][1] - s[v].y;
                float dz = py[u][2] - s[v].z;
                float d2 = dx * dx + dy * dy + dz * dz;
                top3_insert(d2, gi, bd[u], bi[u]);
            }
        }
    }
#pragma unroll
    for (int u = 0; u < YPT; ++u) {
        int y = ybase + u * 256;
        int base = (chunk * N1 + y) * 3;
        pb_d[base] = bd[u][0]; pb_d[base + 1] = bd[u][1]; pb_d[base + 2] = bd[u][2];
        pb_i[base] = bi[u][0]; pb_i[base + 1] = bi[u][1]; pb_i[base + 2] = bi[u][2];
    }
}

__global__ __launch_bounds__(256)
void knn_merge_kernel(const float* __restrict__ pb_d, const int* __restrict__ pb_i,
                      int* __restrict__ knn_idx, float* __restrict__ knn_w) {
    int y = blockIdx.x * 256 + threadIdx.x;
    float bd[3] = {1e30f, 1e30f, 1e30f};
    int bi[3] = {0, 0, 0};
    for (int c = 0; c < KCH; ++c) {
        int base = (c * N1 + y) * 3;
        float d0 = pb_d[base];
        if (d0 >= bd[2]) continue;   // chunk candidates sorted ascending
        top3_insert(d0, pb_i[base], bd, bi);
        top3_insert(pb_d[base + 1], pb_i[base + 1], bd, bi);
        top3_insert(pb_d[base + 2], pb_i[base + 2], bd, bi);
    }
    knn_idx[y * 3]     = bi[0];
    knn_idx[y * 3 + 1] = bi[1];
    knn_idx[y * 3 + 2] = bi[2];
    knn_w[y * 3]     = 1.0f / fmaxf(bd[0], 1e-16f);
    knn_w[y * 3 + 1] = 1.0f / fmaxf(bd[1], 1e-16f);
    knn_w[y * 3 + 2] = 1.0f / fmaxf(bd[2], 1e-16f);
}

__global__ __launch_bounds__(256)
void interp_kernel(const float* __restrict__ x0, const int* __restrict__ knn_idx,
                   const float* __restrict__ knn_w, float* __restrict__ x1) {
    int wave = threadIdx.x >> 6;
    int lane = threadIdx.x & 63;
    int y = blockIdx.x * 4 + wave;
    int i0 = 2 * lane;
    float w0 = knn_w[y * 3], w1 = knn_w[y * 3 + 1], w2 = knn_w[y * 3 + 2];
    int j0 = knn_idx[y * 3], j1 = knn_idx[y * 3 + 1], j2 = knn_idx[y * 3 + 2];
    float inv = 1.0f / (w0 + w1 + w2);
    float2 a = *(const float2*)&x0[j0 * 128 + i0];
    float2 b = *(const float2*)&x0[j1 * 128 + i0];
    float2 c = *(const float2*)&x0[j2 * 128 + i0];
    float2 r;
    r.x = (w0 * a.x + w1 * b.x + w2 * c.x) * inv;
    r.y = (w0 * a.y + w1 * b.y + w2 * c.y) * inv;
    *(float2*)&x1[y * 128 + i0] = r;
}

// ---------------------------------------------------------------------------
// Output head: out[y] = [x1[y] | pos1[y]] @ out_W.T + out_b. One wave per y.
// ---------------------------------------------------------------------------
__global__ __launch_bounds__(256)
void out_kernel(const float* __restrict__ x1, const float* __restrict__ pos1,
                const float* __restrict__ W, const float* __restrict__ b,
                float* __restrict__ out) {
    int wave = threadIdx.x >> 6;
    int lane = threadIdx.x & 63;
    int y = blockIdx.x * 4 + wave;
    float h0 = x1[y * 128 + lane];
    float h1 = x1[y * 128 + 64 + lane];
    float acc[3];
#pragma unroll
    for (int o = 0; o < 3; ++o) {
        float p = h0 * W[o * 131 + lane] + h1 * W[o * 131 + 64 + lane];
#pragma unroll
        for (int off = 1; off < 64; off <<= 1) p += __shfl_xor(p, off, 64);
        acc[o] = p;
    }
    if (lane == 0) {
        float p0 = pos1[y * 3], p1 = pos1[y * 3 + 1], p2 = pos1[y * 3 + 2];
#pragma unroll
        for (int o = 0; o < 3; ++o) {
            out[y * 3 + o] = acc[o] + b[o] + p0 * W[o * 131 + 128]
                           + p1 * W[o * 131 + 129] + p2 * W[o * 131 + 130];
        }
    }
}

// ---------------------------------------------------------------------------
extern "C" void kernel_launch(void* const* d_in, const int* in_sizes, int n_in,
                              void* d_out, int out_size, void* d_ws, size_t ws_size,
                              hipStream_t stream) {
    (void)in_sizes; (void)n_in; (void)out_size; (void)ws_size;
    const float* latent   = (const float*)d_in[0];
    const float* pos0     = (const float*)d_in[1];
    const float* pos1     = (const float*)d_in[2];
    const float* conv_Wl  = (const float*)d_in[5];
    const float* conv_bl  = (const float*)d_in[6];
    const float* conv_Wr  = (const float*)d_in[7];
    const float* conv_br  = (const float*)d_in[8];
    const float* conv_We  = (const float*)d_in[9];
    const float* conv_att = (const float*)d_in[10];
    const float* conv_bias= (const float*)d_in[11];
    const float* lin0_W   = (const float*)d_in[12];
    const float* lin0_b   = (const float*)d_in[13];
    const float* lins_W   = (const float*)d_in[14];
    const float* lins_b   = (const float*)d_in[15];
    const float* out_W    = (const float*)d_in[16];
    const float* out_b    = (const float*)d_in[17];
    float* out = (float*)d_out;

    char* ws = (char*)d_ws;
    float* Wt       = (float*)ws;  ws += (size_t)4 * KP * JTOT * 4;
    float* bias_cat = (float*)ws;  ws += (size_t)4 * JTOT * 4;
    float* Wt0      = (float*)ws;  ws += (size_t)64 * 128 * 4;
    float* bufA     = (float*)ws;  ws += (size_t)N1 * 128 * 4;
    float* bufB     = (float*)ws;  ws += (size_t)N1 * 128 * 4;
    float* xlb      = (float*)ws;  ws += (size_t)N1 * 128 * 4;
    float* xrb      = (float*)ws;  ws += (size_t)N1 * 128 * 4;
    float* linb     = (float*)ws;  ws += (size_t)N1 * 128 * 4;
    float* peb      = (float*)ws;  ws += (size_t)N1 * 128 * 4;
    float* pb_d     = (float*)ws;  ws += (size_t)KCH * N1 * 3 * 4;
    int*   pb_i     = (int*)ws;    ws += (size_t)KCH * N1 * 3 * 4;
    int*   knn_idx  = (int*)ws;    ws += (size_t)N1 * 3 * 4;
    float* knn_w    = (float*)ws;  ws += (size_t)N1 * 3 * 4;

    prep_kernel<<<1100, 256, 0, stream>>>(conv_Wl, conv_Wr, conv_We, lins_W,
                                          conv_bl, conv_br, lins_b, lin0_W,
                                          Wt, bias_cat, Wt0);
    lin0_kernel<<<N0, 128, 0, stream>>>(latent, Wt0, lin0_b, bufA);

    float* cur = bufA; float* nxt = bufB;
    for (int c = 0; c < 2; ++c) {
        fused_gemm_kernel<<<N0 / GR, 256, 0, stream>>>(
            cur, pos0, Wt + (size_t)c * KP * JTOT, bias_cat + c * JTOT,
            xlb, xrb, linb, peb, N0);
        gat_gather_kernel<<<N0 / 4, 256, 0, stream>>>(
            xlb, xrb, peb, linb, conv_att + c * 128, conv_bias + c * 128,
            nxt, N0);
        float* t = cur; cur = nxt; nxt = t;
    }

    knn_part_kernel<<<dim3(N1 / (256 * YPT), KCH), 256, 0, stream>>>(pos0, pos1, pb_d, pb_i);
    knn_merge_kernel<<<N1 / 256, 256, 0, stream>>>(pb_d, pb_i, knn_idx, knn_w);
    interp_kernel<<<N1 / 4, 256, 0, stream>>>(cur, knn_idx, knn_w, bufB);

    cur = bufB; nxt = bufA;
    for (int c = 2; c < 4; ++c) {
        fused_gemm_kernel<<<N1 / GR, 256, 0, stream>>>(
            cur, pos1, Wt + (size_t)c * KP * JTOT, bias_cat + c * JTOT,
            xlb, xrb, linb, peb, N1);
        gat_gather_kernel<<<N1 / 4, 256, 0, stream>>>(
            xlb, xrb, peb, linb, conv_att + c * 128, conv_bias + c * 128,
            nxt, N1);
        float* t = cur; cur = nxt; nxt = t;
    }

    out_kernel<<<N1 / 4, 256, 0, stream>>>(cur, pos1, out_W, out_b, out);
}

// Round 5
// 433.048 us; speedup vs baseline: 2.2802x; 2.2802x over previous
//
#include <hip/hip_runtime.h>
#include <hip/hip_bf16.h>

#define N0 4096
#define N1 16384
#define HID 128
#define LAT 64
#define DIM 3
#define NAUG 21
#define JTOT 512   // xl(128) | xr(128) | lins(128) | pe(128)
#define KP 132     // padded k (131 real + 1 zero row)

__device__ __constant__ int c_aug[NAUG] = {1,2,3,4,5,6,7,8,9,10,11,12,13,14,
                                           15,16,17,18,19,21,24};

// ---------------------------------------------------------------------------
// Prep: transpose/concat weights into Wt[c][k(132, padded)][j(512)],
// bias_cat[c][512], and lin0 weight transpose Wt0[k(64)][j(128)].
// ---------------------------------------------------------------------------
__global__ void prep_kernel(const float* __restrict__ Wl,
                            const float* __restrict__ Wr,
                            const float* __restrict__ We,
                            const float* __restrict__ linsW,
                            const float* __restrict__ bl,
                            const float* __restrict__ br,
                            const float* __restrict__ linsb,
                            const float* __restrict__ lin0W,
                            float* __restrict__ Wt,
                            float* __restrict__ bias_cat,
                            float* __restrict__ Wt0) {
    int tid = blockIdx.x * blockDim.x + threadIdx.x;
    const int NWT = 4 * KP * JTOT;           // 270336
    if (tid < NWT) {
        int c = tid / (KP * JTOT);
        int rem = tid - c * KP * JTOT;
        int k = rem / JTOT;
        int j = rem - k * JTOT;
        float v = 0.0f;
        if (k < 131) {
            if (j < 128)        v = Wl[(c * 128 + j) * 131 + k];
            else if (j < 256)   v = Wr[(c * 128 + (j - 128)) * 131 + k];
            else if (j < 384)   v = linsW[(c * 128 + (j - 256)) * 131 + k];
            else                v = (k >= 128) ? We[(c * 128 + (j - 384)) * 3 + (k - 128)]
                                               : 0.0f;
        }
        Wt[tid] = v;
    } else if (tid < NWT + 4 * JTOT) {       // bias_cat
        int idx = tid - NWT;
        int c = idx / JTOT;
        int j = idx - c * JTOT;
        float v;
        if (j < 128)        v = bl[c * 128 + j];
        else if (j < 256)   v = br[c * 128 + (j - 128)];
        else if (j < 384)   v = linsb[c * 128 + (j - 256)];
        else                v = 0.0f;
        bias_cat[idx] = v;
    } else if (tid < NWT + 4 * JTOT + 64 * 128) {  // Wt0
        int idx = tid - NWT - 4 * JTOT;
        int k = idx / 128;
        int j = idx - k * 128;
        Wt0[idx] = lin0W[j * 64 + k];
    }
}

// ---------------------------------------------------------------------------
// lin0: x0[n][j] = latent[n] . lin0_W[j] + b[j]   (4096x64 @ 64x128)
// ---------------------------------------------------------------------------
__global__ void lin0_kernel(const float* __restrict__ latent,
                            const float* __restrict__ Wt0,
                            const float* __restrict__ b,
                            float* __restrict__ x0) {
    __shared__ float lrow[64];
    int n = blockIdx.x;
    int j = threadIdx.x;
    if (j < 64) lrow[j] = latent[n * 64 + j];
    __syncthreads();
    float acc = b[j];
#pragma unroll 8
    for (int k = 0; k < 64; ++k) acc += lrow[k] * Wt0[k * 128 + j];
    x0[n * 128 + j] = acc;
}

// ---------------------------------------------------------------------------
// Fused per-layer GEMM, software-pipelined with STATIC double buffers
// (R4's dynamic-indexed wv[2][..] spilled to scratch: 1 GB of HBM traffic).
// Pattern: preload c0->A; loop 16x {load B; compute A; load A; compute B};
// epilogue compute A.  All buffer indices compile-time constant.
// ---------------------------------------------------------------------------
#define GR 16   // rows per block
__global__ __launch_bounds__(256, 4)
void fused_gemm_kernel(const float* __restrict__ x,
                       const float* __restrict__ pos,
                       const float* __restrict__ Wt,       // [132][512] this layer
                       const float* __restrict__ bias_cat, // [512] this layer
                       float* __restrict__ xl, float* __restrict__ xr,
                       float* __restrict__ lin, float* __restrict__ pe,
                       int N) {
    __shared__ float h[GR][KP];
    int n0 = blockIdx.x * GR;
    int tid = threadIdx.x;
    for (int idx = tid; idx < GR * KP; idx += 256) {
        int r = idx / KP;
        int k = idx - r * KP;
        float v;
        if (k < 128)      v = x[(n0 + r) * 128 + k];
        else if (k < 131) v = pos[(n0 + r) * 3 + (k - 128)];
        else              v = 0.0f;
        h[r][k] = v;
    }
    __syncthreads();

    int jg = tid & 63;
    int rg = tid >> 6;
    int j0 = jg * 8;
    int r0 = rg * 4;

    float acc[4][8];
    {
        float bv[8];
        *(float4*)&bv[0] = *(const float4*)&bias_cat[j0];
        *(float4*)&bv[4] = *(const float4*)&bias_cat[j0 + 4];
#pragma unroll
        for (int r = 0; r < 4; ++r)
#pragma unroll
            for (int c = 0; c < 8; ++c) acc[r][c] = bv[c];
    }

    float wa[4][8], wb[4][8];

#define LOADW(dst, kbase)                                                      \
    {                                                                          \
        _Pragma("unroll")                                                      \
        for (int kk = 0; kk < 4; ++kk) {                                       \
            *(float4*)&dst[kk][0] = *(const float4*)&Wt[(kbase + kk) * JTOT + j0];     \
            *(float4*)&dst[kk][4] = *(const float4*)&Wt[(kbase + kk) * JTOT + j0 + 4]; \
        }                                                                      \
    }

#define COMPUTE(w, kbase)                                                      \
    {                                                                          \
        float ha[4][4];                                                        \
        _Pragma("unroll")                                                      \
        for (int r = 0; r < 4; ++r)                                            \
            *(float4*)&ha[r][0] = *(const float4*)&h[r0 + r][kbase];           \
        _Pragma("unroll")                                                      \
        for (int kk = 0; kk < 4; ++kk)                                         \
            _Pragma("unroll")                                                  \
            for (int r = 0; r < 4; ++r)                                        \
                _Pragma("unroll")                                              \
                for (int c = 0; c < 8; ++c)                                    \
                    acc[r][c] += ha[r][kk] * w[kk][c];                         \
    }

    LOADW(wa, 0);
    int k = 0;
    for (int it = 0; it < 16; ++it) {   // chunks c0..c31 pipelined
        LOADW(wb, k + 4);
        COMPUTE(wa, k);
        LOADW(wa, k + 8);               // at it=15 loads c32 (k=128..131)
        COMPUTE(wb, k + 4);
        k += 8;
    }
    COMPUTE(wa, 128);                   // final chunk c32

#undef LOADW
#undef COMPUTE

    int seg = j0 >> 7;          // 0..3
    int jj = j0 & 127;
    float* dst = (seg == 0) ? xl : (seg == 1) ? xr : (seg == 2) ? lin : pe;
#pragma unroll
    for (int r = 0; r < 4; ++r) {
        float* p = &dst[(size_t)(n0 + r0 + r) * 128 + jj];
        *(float4*)p       = make_float4(acc[r][0], acc[r][1], acc[r][2], acc[r][3]);
        *(float4*)(p + 4) = make_float4(acc[r][4], acc[r][5], acc[r][6], acc[r][7]);
    }
}

// ---------------------------------------------------------------------------
// GATv2 gather: per-lane partial dots, then batched butterfly reduction.
// ---------------------------------------------------------------------------
__global__ __launch_bounds__(256)
void gat_gather_kernel(const float* __restrict__ xl, const float* __restrict__ xr,
                       const float* __restrict__ pe, const float* __restrict__ lin,
                       const float* __restrict__ att, const float* __restrict__ bias,
                       float* __restrict__ xout, int N) {
    int wave = threadIdx.x >> 6;
    int lane = threadIdx.x & 63;
    int d = blockIdx.x * 4 + wave;
    if (d >= N) return;
    int i0 = 2 * lane;

    float att0 = att[i0], att1 = att[i0 + 1];
    float2 xld = *(const float2*)&xl[d * 128 + i0];
    float2 xrd = *(const float2*)&xr[d * 128 + i0];
    float2 ped = *(const float2*)&pe[d * 128 + i0];

    float a[NAUG + 1];
    float xs0[NAUG], xs1[NAUG];
    float pes0 = 0.0f, pes1 = 0.0f;

#pragma unroll
    for (int k = 0; k < NAUG; ++k) {
        int s = d - c_aug[k];
        if (s < 0) s += N;
        float2 xls = *(const float2*)&xl[s * 128 + i0];
        float2 pes = *(const float2*)&pe[s * 128 + i0];
        xs0[k] = xls.x; xs1[k] = xls.y;
        pes0 += pes.x;  pes1 += pes.y;
        float m0 = xls.x + xrd.x + ped.x - pes.x;
        float m1 = xls.y + xrd.y + ped.y - pes.y;
        m0 = m0 > 0.0f ? m0 : 0.2f * m0;
        m1 = m1 > 0.0f ? m1 : 0.2f * m1;
        a[k] = att0 * m0 + att1 * m1;
    }
    {   // self loop: eattr = mean over in-edges = ped - mean(pes)
        const float inv21 = 1.0f / 21.0f;
        float m0 = xld.x + xrd.x + (ped.x - pes0 * inv21);
        float m1 = xld.y + xrd.y + (ped.y - pes1 * inv21);
        m0 = m0 > 0.0f ? m0 : 0.2f * m0;
        m1 = m1 > 0.0f ? m1 : 0.2f * m1;
        a[NAUG] = att0 * m0 + att1 * m1;
    }

#pragma unroll
    for (int off = 1; off < 64; off <<= 1) {
#pragma unroll
        for (int k = 0; k <= NAUG; ++k)
            a[k] += __shfl_xor(a[k], off, 64);
    }

    float amax = a[0];
#pragma unroll
    for (int k = 1; k <= NAUG; ++k) amax = fmaxf(amax, a[k]);
    float den = 0.0f;
#pragma unroll
    for (int k = 0; k <= NAUG; ++k) { a[k] = __expf(a[k] - amax); den += a[k]; }
    float inv = 1.0f / (den + 1e-16f);

    float o0 = 0.0f, o1 = 0.0f;
#pragma unroll
    for (int k = 0; k < NAUG; ++k) {
        float al = a[k] * inv;
        o0 += al * xs0[k];
        o1 += al * xs1[k];
    }
    {
        float al = a[NAUG] * inv;
        o0 += al * xld.x;
        o1 += al * xld.y;
    }
    o0 += bias[i0];
    o1 += bias[i0 + 1];
    o0 = o0 > 0.0f ? o0 : __expf(o0) - 1.0f;
    o1 = o1 > 0.0f ? o1 : __expf(o1) - 1.0f;
    float2 l2 = *(const float2*)&lin[d * 128 + i0];
    float2 res;
    res.x = o0 + l2.x;
    res.y = o1 + l2.y;
    *(float2*)&xout[d * 128 + i0] = res;
}

// ---------------------------------------------------------------------------
// knn: float4-padded LDS points, 4 y per thread, 32 chunks of 128 points.
// ---------------------------------------------------------------------------
#define KCH 32
#define KCS 128   // 4096 / 32
#define YPT 4

__device__ __forceinline__ void top3_insert(float d2, int gi,
                                            float (&bd)[3], int (&bi)[3]) {
    if (d2 < bd[2]) {
        if (d2 < bd[0])      { bd[2]=bd[1]; bi[2]=bi[1]; bd[1]=bd[0]; bi[1]=bi[0]; bd[0]=d2; bi[0]=gi; }
        else if (d2 < bd[1]) { bd[2]=bd[1]; bi[2]=bi[1]; bd[1]=d2;    bi[1]=gi; }
        else                 { bd[2]=d2;    bi[2]=gi; }
    }
}

__global__ __launch_bounds__(256)
void knn_part_kernel(const float* __restrict__ pos0, const float* __restrict__ pos1,
                     float* __restrict__ pb_d, int* __restrict__ pb_i) {
    __shared__ float4 sx[KCS];
    int tid = threadIdx.x;
    int chunk = blockIdx.y;
    for (int t = tid; t < KCS; t += 256) {
        const float* p = &pos0[(chunk * KCS + t) * 3];
        sx[t] = make_float4(p[0], p[1], p[2], 0.0f);
    }
    __syncthreads();
    int ybase = blockIdx.x * (256 * YPT) + tid;
    float py[YPT][3];
#pragma unroll
    for (int u = 0; u < YPT; ++u) {
        int y = ybase + u * 256;
        py[u][0] = pos1[y * 3];
        py[u][1] = pos1[y * 3 + 1];
        py[u][2] = pos1[y * 3 + 2];
    }
    float bd[YPT][3]; int bi[YPT][3];
#pragma unroll
    for (int u = 0; u < YPT; ++u) {
        bd[u][0] = bd[u][1] = bd[u][2] = 1e30f;
        bi[u][0] = bi[u][1] = bi[u][2] = 0;
    }
    int gbase = chunk * KCS;
    for (int i = 0; i < KCS; i += 4) {
        float4 s[4];
#pragma unroll
        for (int v = 0; v < 4; ++v) s[v] = sx[i + v];
#pragma unroll
        for (int v = 0; v < 4; ++v) {
            int gi = gbase + i + v;
#pragma unroll
            for (int u = 0; u < YPT; ++u) {
                float dx = py[u][0] - s[v].x;
                float dy = py[u][1] - s[v].y;
                float dz = py[u][2] - s[v].z;
                float d2 = dx * dx + dy * dy + dz * dz;
                top3_insert(d2, gi, bd[u], bi[u]);
            }
        }
    }
#pragma unroll
    for (int u = 0; u < YPT; ++u) {
        int y = ybase + u * 256;
        int base = (chunk * N1 + y) * 3;
        pb_d[base] = bd[u][0]; pb_d[base + 1] = bd[u][1]; pb_d[base + 2] = bd[u][2];
        pb_i[base] = bi[u][0]; pb_i[base + 1] = bi[u][1]; pb_i[base + 2] = bi[u][2];
    }
}

__global__ __launch_bounds__(256)
void knn_merge_kernel(const float* __restrict__ pb_d, const int* __restrict__ pb_i,
                      int* __restrict__ knn_idx, float* __restrict__ knn_w) {
    int y = blockIdx.x * 256 + threadIdx.x;
    float bd[3] = {1e30f, 1e30f, 1e30f};
    int bi[3] = {0, 0, 0};
    for (int c = 0; c < KCH; ++c) {
        int base = (c * N1 + y) * 3;
        float d0 = pb_d[base];
        if (d0 >= bd[2]) continue;   // chunk candidates sorted ascending
        top3_insert(d0, pb_i[base], bd, bi);
        top3_insert(pb_d[base + 1], pb_i[base + 1], bd, bi);
        top3_insert(pb_d[base + 2], pb_i[base + 2], bd, bi);
    }
    knn_idx[y * 3]     = bi[0];
    knn_idx[y * 3 + 1] = bi[1];
    knn_idx[y * 3 + 2] = bi[2];
    knn_w[y * 3]     = 1.0f / fmaxf(bd[0], 1e-16f);
    knn_w[y * 3 + 1] = 1.0f / fmaxf(bd[1], 1e-16f);
    knn_w[y * 3 + 2] = 1.0f / fmaxf(bd[2], 1e-16f);
}

__global__ __launch_bounds__(256)
void interp_kernel(const float* __restrict__ x0, const int* __restrict__ knn_idx,
                   const float* __restrict__ knn_w, float* __restrict__ x1) {
    int wave = threadIdx.x >> 6;
    int lane = threadIdx.x & 63;
    int y = blockIdx.x * 4 + wave;
    int i0 = 2 * lane;
    float w0 = knn_w[y * 3], w1 = knn_w[y * 3 + 1], w2 = knn_w[y * 3 + 2];
    int j0 = knn_idx[y * 3], j1 = knn_idx[y * 3 + 1], j2 = knn_idx[y * 3 + 2];
    float inv = 1.0f / (w0 + w1 + w2);
    float2 a = *(const float2*)&x0[j0 * 128 + i0];
    float2 b = *(const float2*)&x0[j1 * 128 + i0];
    float2 c = *(const float2*)&x0[j2 * 128 + i0];
    float2 r;
    r.x = (w0 * a.x + w1 * b.x + w2 * c.x) * inv;
    r.y = (w0 * a.y + w1 * b.y + w2 * c.y) * inv;
    *(float2*)&x1[y * 128 + i0] = r;
}

// ---------------------------------------------------------------------------
// Output head: out[y] = [x1[y] | pos1[y]] @ out_W.T + out_b. One wave per y.
// ---------------------------------------------------------------------------
__global__ __launch_bounds__(256)
void out_kernel(const float* __restrict__ x1, const float* __restrict__ pos1,
                const float* __restrict__ W, const float* __restrict__ b,
                float* __restrict__ out) {
    int wave = threadIdx.x >> 6;
    int lane = threadIdx.x & 63;
    int y = blockIdx.x * 4 + wave;
    float h0 = x1[y * 128 + lane];
    float h1 = x1[y * 128 + 64 + lane];
    float acc[3];
#pragma unroll
    for (int o = 0; o < 3; ++o) {
        float p = h0 * W[o * 131 + lane] + h1 * W[o * 131 + 64 + lane];
#pragma unroll
        for (int off = 1; off < 64; off <<= 1) p += __shfl_xor(p, off, 64);
        acc[o] = p;
    }
    if (lane == 0) {
        float p0 = pos1[y * 3], p1 = pos1[y * 3 + 1], p2 = pos1[y * 3 + 2];
#pragma unroll
        for (int o = 0; o < 3; ++o) {
            out[y * 3 + o] = acc[o] + b[o] + p0 * W[o * 131 + 128]
                           + p1 * W[o * 131 + 129] + p2 * W[o * 131 + 130];
        }
    }
}

// ---------------------------------------------------------------------------
extern "C" void kernel_launch(void* const* d_in, const int* in_sizes, int n_in,
                              void* d_out, int out_size, void* d_ws, size_t ws_size,
                              hipStream_t stream) {
    (void)in_sizes; (void)n_in; (void)out_size; (void)ws_size;
    const float* latent   = (const float*)d_in[0];
    const float* pos0     = (const float*)d_in[1];
    const float* pos1     = (const float*)d_in[2];
    const float* conv_Wl  = (const float*)d_in[5];
    const float* conv_bl  = (const float*)d_in[6];
    const float* conv_Wr  = (const float*)d_in[7];
    const float* conv_br  = (const float*)d_in[8];
    const float* conv_We  = (const float*)d_in[9];
    const float* conv_att = (const float*)d_in[10];
    const float* conv_bias= (const float*)d_in[11];
    const float* lin0_W   = (const float*)d_in[12];
    const float* lin0_b   = (const float*)d_in[13];
    const float* lins_W   = (const float*)d_in[14];
    const float* lins_b   = (const float*)d_in[15];
    const float* out_W    = (const float*)d_in[16];
    const float* out_b    = (const float*)d_in[17];
    float* out = (float*)d_out;

    char* ws = (char*)d_ws;
    float* Wt       = (float*)ws;  ws += (size_t)4 * KP * JTOT * 4;
    float* bias_cat = (float*)ws;  ws += (size_t)4 * JTOT * 4;
    float* Wt0      = (float*)ws;  ws += (size_t)64 * 128 * 4;
    float* bufA     = (float*)ws;  ws += (size_t)N1 * 128 * 4;
    float* bufB     = (float*)ws;  ws += (size_t)N1 * 128 * 4;
    float* xlb      = (float*)ws;  ws += (size_t)N1 * 128 * 4;
    float* xrb      = (float*)ws;  ws += (size_t)N1 * 128 * 4;
    float* linb     = (float*)ws;  ws += (size_t)N1 * 128 * 4;
    float* peb      = (float*)ws;  ws += (size_t)N1 * 128 * 4;
    float* pb_d     = (float*)ws;  ws += (size_t)KCH * N1 * 3 * 4;
    int*   pb_i     = (int*)ws;    ws += (size_t)KCH * N1 * 3 * 4;
    int*   knn_idx  = (int*)ws;    ws += (size_t)N1 * 3 * 4;
    float* knn_w    = (float*)ws;  ws += (size_t)N1 * 3 * 4;

    prep_kernel<<<1100, 256, 0, stream>>>(conv_Wl, conv_Wr, conv_We, lins_W,
                                          conv_bl, conv_br, lins_b, lin0_W,
                                          Wt, bias_cat, Wt0);
    lin0_kernel<<<N0, 128, 0, stream>>>(latent, Wt0, lin0_b, bufA);

    float* cur = bufA; float* nxt = bufB;
    for (int c = 0; c < 2; ++c) {
        fused_gemm_kernel<<<N0 / GR, 256, 0, stream>>>(
            cur, pos0, Wt + (size_t)c * KP * JTOT, bias_cat + c * JTOT,
            xlb, xrb, linb, peb, N0);
        gat_gather_kernel<<<N0 / 4, 256, 0, stream>>>(
            xlb, xrb, peb, linb, conv_att + c * 128, conv_bias + c * 128,
            nxt, N0);
        float* t = cur; cur = nxt; nxt = t;
    }

    knn_part_kernel<<<dim3(N1 / (256 * YPT), KCH), 256, 0, stream>>>(pos0, pos1, pb_d, pb_i);
    knn_merge_kernel<<<N1 / 256, 256, 0, stream>>>(pb_d, pb_i, knn_idx, knn_w);
    interp_kernel<<<N1 / 4, 256, 0, stream>>>(cur, knn_idx, knn_w, bufB);

    cur = bufB; nxt = bufA;
    for (int c = 2; c < 4; ++c) {
        fused_gemm_kernel<<<N1 / GR, 256, 0, stream>>>(
            cur, pos1, Wt + (size_t)c * KP * JTOT, bias_cat + c * JTOT,
            xlb, xrb, linb, peb, N1);
        gat_gather_kernel<<<N1 / 4, 256, 0, stream>>>(
            xlb, xrb, peb, linb, conv_att + c * 128, conv_bias + c * 128,
            nxt, N1);
        float* t = cur; cur = nxt; nxt = t;
    }

    out_kernel<<<N1 / 4, 256, 0, stream>>>(cur, pos1, out_W, out_b, out);
}

// Round 6
// 329.807 us; speedup vs baseline: 2.9939x; 1.3130x over previous
//
#include <hip/hip_runtime.h>
#include <hip/hip_bf16.h>

#define N0 4096
#define N1 16384
#define HID 128
#define LAT 64
#define DIM 3
#define NAUG 21
#define JTOT 512    // xl(128) | xr(128) | lins(128) | pe(128)
#define KPAD 160    // K padded to 5 groups of 32 (131 real)
#define NT 32       // 512/16 n-tiles
#define NG 5        // k-groups per tile row

typedef __attribute__((ext_vector_type(8))) short bf16x8;
typedef __attribute__((ext_vector_type(4))) float f32x4;

__device__ __constant__ int c_aug[NAUG] = {1,2,3,4,5,6,7,8,9,10,11,12,13,14,
                                           15,16,17,18,19,21,24};

__device__ __forceinline__ unsigned short f2bf(float v) {
    __hip_bfloat16 b = __float2bfloat16(v);
    return *reinterpret_cast<unsigned short*>(&b);
}

// ---------------------------------------------------------------------------
// Prep: build Wswz[c][nt(32)][g(5)][l(64)][j(8)] bf16 B-fragments,
// bias_cat[c][512] f32, Wt0[k(64)][j(128)] f32 for lin0.
// B[k][n]: k = g*32 + (l>>4)*8 + j, n = nt*16 + (l&15).
// ---------------------------------------------------------------------------
#define WSWZ_PER_LAYER 81920   // 160*512
__global__ void prep_kernel(const float* __restrict__ Wl,
                            const float* __restrict__ Wr,
                            const float* __restrict__ We,
                            const float* __restrict__ linsW,
                            const float* __restrict__ bl,
                            const float* __restrict__ br,
                            const float* __restrict__ linsb,
                            const float* __restrict__ lin0W,
                            unsigned short* __restrict__ Wswz,
                            float* __restrict__ bias_cat,
                            float* __restrict__ Wt0) {
    int tid = blockIdx.x * blockDim.x + threadIdx.x;
    const int NSWZ = 4 * WSWZ_PER_LAYER;     // 327680
    if (tid < NSWZ) {
        int c = tid / WSWZ_PER_LAYER;
        int r = tid - c * WSWZ_PER_LAYER;    // ((nt*5+g)*64+l)*8+j
        int nt = r / 2560;
        int g  = (r / 512) % 5;
        int l  = (r / 8) % 64;
        int j  = r % 8;
        int k  = g * 32 + (l >> 4) * 8 + j;
        int n  = nt * 16 + (l & 15);
        float v = 0.0f;
        if (k < 131) {
            if (n < 128)      v = Wl[(c * 128 + n) * 131 + k];
            else if (n < 256) v = Wr[(c * 128 + (n - 128)) * 131 + k];
            else if (n < 384) v = linsW[(c * 128 + (n - 256)) * 131 + k];
            else              v = (k >= 128) ? We[(c * 128 + (n - 384)) * 3 + (k - 128)]
                                             : 0.0f;
        }
        Wswz[tid] = f2bf(v);
    } else if (tid < NSWZ + 4 * JTOT) {      // bias_cat
        int idx = tid - NSWZ;
        int c = idx / JTOT;
        int j = idx - c * JTOT;
        float v;
        if (j < 128)        v = bl[c * 128 + j];
        else if (j < 256)   v = br[c * 128 + (j - 128)];
        else if (j < 384)   v = linsb[c * 128 + (j - 256)];
        else                v = 0.0f;
        bias_cat[idx] = v;
    } else if (tid < NSWZ + 4 * JTOT + 64 * 128) {  // Wt0
        int idx = tid - NSWZ - 4 * JTOT;
        int k = idx / 128;
        int j = idx - k * 128;
        Wt0[idx] = lin0W[j * 64 + k];
    }
}

// ---------------------------------------------------------------------------
// lin0: x0[n][j] = latent[n] . lin0_W[j] + b[j]   (4096x64 @ 64x128)
// ---------------------------------------------------------------------------
__global__ void lin0_kernel(const float* __restrict__ latent,
                            const float* __restrict__ Wt0,
                            const float* __restrict__ b,
                            float* __restrict__ x0) {
    __shared__ float lrow[64];
    int n = blockIdx.x;
    int j = threadIdx.x;
    if (j < 64) lrow[j] = latent[n * 64 + j];
    __syncthreads();
    float acc = b[j];
#pragma unroll 8
    for (int k = 0; k < 64; ++k) acc += lrow[k] * Wt0[k * 128 + j];
    x0[n * 128 + j] = acc;
}

// ---------------------------------------------------------------------------
// Convert h=[x|pos|0] rows to A-fragment-swizzled bf16:
// hswz[mt][g(5)][l(64)][j(8)]: element = h[mt*16 + (l&15)][g*32 + (l>>4)*8 + j].
// One thread per 8-element chunk; 16B coalesced stores.
// ---------------------------------------------------------------------------
__global__ __launch_bounds__(256)
void convert_kernel(const float* __restrict__ x, const float* __restrict__ pos,
                    unsigned short* __restrict__ hswz, int nchunks) {
    int t = blockIdx.x * 256 + threadIdx.x;
    if (t >= nchunks) return;
    int l = t & 63;
    int g = (t >> 6) % 5;
    int mt = t / 320;
    int m = mt * 16 + (l & 15);
    int kbase = g * 32 + (l >> 4) * 8;
    unsigned short o[8];
    if (kbase + 8 <= 128) {
        const float* p = &x[m * 128 + kbase];
        float4 v0 = *(const float4*)p;
        float4 v1 = *(const float4*)(p + 4);
        o[0] = f2bf(v0.x); o[1] = f2bf(v0.y); o[2] = f2bf(v0.z); o[3] = f2bf(v0.w);
        o[4] = f2bf(v1.x); o[5] = f2bf(v1.y); o[6] = f2bf(v1.z); o[7] = f2bf(v1.w);
    } else {
#pragma unroll
        for (int j = 0; j < 8; ++j) {
            int k = kbase + j;
            float v = (k < 128) ? x[m * 128 + k]
                    : (k < 131) ? pos[m * 3 + (k - 128)] : 0.0f;
            o[j] = f2bf(v);
        }
    }
    *(bf16x8*)&hswz[t * 8] = *(bf16x8*)o;
}

// ---------------------------------------------------------------------------
// MFMA GEMM: [xl|xr|lin|pe](M x 512) = h(M x 160) @ W + bias.
// Block = 4 waves, all on the same 32-row M-pair; wave w owns n-tiles
// w*8..w*8+7 (i.e., exactly one 128-col output array). No LDS; A and B
// fragments pre-swizzled so every load is a coalesced 1KB dwordx4.
// ---------------------------------------------------------------------------
__global__ __launch_bounds__(256)
void gemm_mfma_kernel(const unsigned short* __restrict__ hswz,
                      const unsigned short* __restrict__ Wswz,  // this layer
                      const float* __restrict__ bias_cat,       // this layer
                      float* __restrict__ xl, float* __restrict__ xr,
                      float* __restrict__ lin, float* __restrict__ pe,
                      int M) {
    int w = threadIdx.x >> 6;
    int l = threadIdx.x & 63;
    int quad = l >> 4, lcol = l & 15;
    int mt0 = blockIdx.x * 2;

    bf16x8 a[2][NG];
#pragma unroll
    for (int i = 0; i < 2; ++i)
#pragma unroll
        for (int g = 0; g < NG; ++g)
            a[i][g] = *(const bf16x8*)&hswz[(size_t)(((mt0 + i) * NG + g) * 64 + l) * 8];

    float* dst = (w == 0) ? xl : (w == 1) ? xr : (w == 2) ? lin : pe;

#pragma unroll
    for (int q = 0; q < 8; ++q) {
        int nt = w * 8 + q;
        bf16x8 b[NG];
#pragma unroll
        for (int g = 0; g < NG; ++g)
            b[g] = *(const bf16x8*)&Wswz[(size_t)((nt * NG + g) * 64 + l) * 8];
        float bias = bias_cat[nt * 16 + lcol];
        f32x4 c0 = {bias, bias, bias, bias};
        f32x4 c1 = {bias, bias, bias, bias};
#pragma unroll
        for (int g = 0; g < NG; ++g) {
            c0 = __builtin_amdgcn_mfma_f32_16x16x32_bf16(a[0][g], b[g], c0, 0, 0, 0);
            c1 = __builtin_amdgcn_mfma_f32_16x16x32_bf16(a[1][g], b[g], c1, 0, 0, 0);
        }
        int jj = q * 16 + lcol;
#pragma unroll
        for (int r = 0; r < 4; ++r) {
            int m0 = mt0 * 16 + quad * 4 + r;
            dst[(size_t)m0 * 128 + jj] = c0[r];
            dst[(size_t)(m0 + 16) * 128 + jj] = c1[r];
        }
    }
}

// ---------------------------------------------------------------------------
// GATv2 gather: per-lane partial dots, then batched butterfly reduction.
// ---------------------------------------------------------------------------
__global__ __launch_bounds__(256)
void gat_gather_kernel(const float* __restrict__ xl, const float* __restrict__ xr,
                       const float* __restrict__ pe, const float* __restrict__ lin,
                       const float* __restrict__ att, const float* __restrict__ bias,
                       float* __restrict__ xout, int N) {
    int wave = threadIdx.x >> 6;
    int lane = threadIdx.x & 63;
    int d = blockIdx.x * 4 + wave;
    if (d >= N) return;
    int i0 = 2 * lane;

    float att0 = att[i0], att1 = att[i0 + 1];
    float2 xld = *(const float2*)&xl[d * 128 + i0];
    float2 xrd = *(const float2*)&xr[d * 128 + i0];
    float2 ped = *(const float2*)&pe[d * 128 + i0];

    float a[NAUG + 1];
    float xs0[NAUG], xs1[NAUG];
    float pes0 = 0.0f, pes1 = 0.0f;

#pragma unroll
    for (int k = 0; k < NAUG; ++k) {
        int s = d - c_aug[k];
        if (s < 0) s += N;
        float2 xls = *(const float2*)&xl[s * 128 + i0];
        float2 pes = *(const float2*)&pe[s * 128 + i0];
        xs0[k] = xls.x; xs1[k] = xls.y;
        pes0 += pes.x;  pes1 += pes.y;
        float m0 = xls.x + xrd.x + ped.x - pes.x;
        float m1 = xls.y + xrd.y + ped.y - pes.y;
        m0 = m0 > 0.0f ? m0 : 0.2f * m0;
        m1 = m1 > 0.0f ? m1 : 0.2f * m1;
        a[k] = att0 * m0 + att1 * m1;
    }
    {   // self loop: eattr = mean over in-edges = ped - mean(pes)
        const float inv21 = 1.0f / 21.0f;
        float m0 = xld.x + xrd.x + (ped.x - pes0 * inv21);
        float m1 = xld.y + xrd.y + (ped.y - pes1 * inv21);
        m0 = m0 > 0.0f ? m0 : 0.2f * m0;
        m1 = m1 > 0.0f ? m1 : 0.2f * m1;
        a[NAUG] = att0 * m0 + att1 * m1;
    }

#pragma unroll
    for (int off = 1; off < 64; off <<= 1) {
#pragma unroll
        for (int k = 0; k <= NAUG; ++k)
            a[k] += __shfl_xor(a[k], off, 64);
    }

    float amax = a[0];
#pragma unroll
    for (int k = 1; k <= NAUG; ++k) amax = fmaxf(amax, a[k]);
    float den = 0.0f;
#pragma unroll
    for (int k = 0; k <= NAUG; ++k) { a[k] = __expf(a[k] - amax); den += a[k]; }
    float inv = 1.0f / (den + 1e-16f);

    float o0 = 0.0f, o1 = 0.0f;
#pragma unroll
    for (int k = 0; k < NAUG; ++k) {
        float al = a[k] * inv;
        o0 += al * xs0[k];
        o1 += al * xs1[k];
    }
    {
        float al = a[NAUG] * inv;
        o0 += al * xld.x;
        o1 += al * xld.y;
    }
    o0 += bias[i0];
    o1 += bias[i0 + 1];
    o0 = o0 > 0.0f ? o0 : __expf(o0) - 1.0f;
    o1 = o1 > 0.0f ? o1 : __expf(o1) - 1.0f;
    float2 l2 = *(const float2*)&lin[d * 128 + i0];
    float2 res;
    res.x = o0 + l2.x;
    res.y = o1 + l2.y;
    *(float2*)&xout[d * 128 + i0] = res;
}

// ---------------------------------------------------------------------------
// knn: float4-padded LDS points, 4 y per thread, 32 chunks of 128 points.
// ---------------------------------------------------------------------------
#define KCH 32
#define KCS 128   // 4096 / 32
#define YPT 4

__device__ __forceinline__ void top3_insert(float d2, int gi,
                                            float (&bd)[3], int (&bi)[3]) {
    if (d2 < bd[2]) {
        if (d2 < bd[0])      { bd[2]=bd[1]; bi[2]=bi[1]; bd[1]=bd[0]; bi[1]=bi[0]; bd[0]=d2; bi[0]=gi; }
        else if (d2 < bd[1]) { bd[2]=bd[1]; bi[2]=bi[1]; bd[1]=d2;    bi[1]=gi; }
        else                 { bd[2]=d2;    bi[2]=gi; }
    }
}

__global__ __launch_bounds__(256)
void knn_part_kernel(const float* __restrict__ pos0, const float* __restrict__ pos1,
                     float* __restrict__ pb_d, int* __restrict__ pb_i) {
    __shared__ float4 sx[KCS];
    int tid = threadIdx.x;
    int chunk = blockIdx.y;
    for (int t = tid; t < KCS; t += 256) {
        const float* p = &pos0[(chunk * KCS + t) * 3];
        sx[t] = make_float4(p[0], p[1], p[2], 0.0f);
    }
    __syncthreads();
    int ybase = blockIdx.x * (256 * YPT) + tid;
    float py[YPT][3];
#pragma unroll
    for (int u = 0; u < YPT; ++u) {
        int y = ybase + u * 256;
        py[u][0] = pos1[y * 3];
        py[u][1] = pos1[y * 3 + 1];
        py[u][2] = pos1[y * 3 + 2];
    }
    float bd[YPT][3]; int bi[YPT][3];
#pragma unroll
    for (int u = 0; u < YPT; ++u) {
        bd[u][0] = bd[u][1] = bd[u][2] = 1e30f;
        bi[u][0] = bi[u][1] = bi[u][2] = 0;
    }
    int gbase = chunk * KCS;
    for (int i = 0; i < KCS; i += 4) {
        float4 s[4];
#pragma unroll
        for (int v = 0; v < 4; ++v) s[v] = sx[i + v];
#pragma unroll
        for (int v = 0; v < 4; ++v) {
            int gi = gbase + i + v;
#pragma unroll
            for (int u = 0; u < YPT; ++u) {
                float dx = py[u][0] - s[v].x;
                float dy = py[u][1] - s[v].y;
                float dz = py[u][2] - s[v].z;
                float d2 = dx * dx + dy * dy + dz * dz;
                top3_insert(d2, gi, bd[u], bi[u]);
            }
        }
    }
#pragma unroll
    for (int u = 0; u < YPT; ++u) {
        int y = ybase + u * 256;
        int base = (chunk * N1 + y) * 3;
        pb_d[base] = bd[u][0]; pb_d[base + 1] = bd[u][1]; pb_d[base + 2] = bd[u][2];
        pb_i[base] = bi[u][0]; pb_i[base + 1] = bi[u][1]; pb_i[base + 2] = bi[u][2];
    }
}

__global__ __launch_bounds__(256)
void knn_merge_kernel(const float* __restrict__ pb_d, const int* __restrict__ pb_i,
                      int* __restrict__ knn_idx, float* __restrict__ knn_w) {
    int y = blockIdx.x * 256 + threadIdx.x;
    float bd[3] = {1e30f, 1e30f, 1e30f};
    int bi[3] = {0, 0, 0};
    for (int c = 0; c < KCH; ++c) {
        int base = (c * N1 + y) * 3;
        float d0 = pb_d[base];
        if (d0 >= bd[2]) continue;   // chunk candidates sorted ascending
        top3_insert(d0, pb_i[base], bd, bi);
        top3_insert(pb_d[base + 1], pb_i[base + 1], bd, bi);
        top3_insert(pb_d[base + 2], pb_i[base + 2], bd, bi);
    }
    knn_idx[y * 3]     = bi[0];
    knn_idx[y * 3 + 1] = bi[1];
    knn_idx[y * 3 + 2] = bi[2];
    knn_w[y * 3]     = 1.0f / fmaxf(bd[0], 1e-16f);
    knn_w[y * 3 + 1] = 1.0f / fmaxf(bd[1], 1e-16f);
    knn_w[y * 3 + 2] = 1.0f / fmaxf(bd[2], 1e-16f);
}

__global__ __launch_bounds__(256)
void interp_kernel(const float* __restrict__ x0, const int* __restrict__ knn_idx,
                   const float* __restrict__ knn_w, float* __restrict__ x1) {
    int wave = threadIdx.x >> 6;
    int lane = threadIdx.x & 63;
    int y = blockIdx.x * 4 + wave;
    int i0 = 2 * lane;
    float w0 = knn_w[y * 3], w1 = knn_w[y * 3 + 1], w2 = knn_w[y * 3 + 2];
    int j0 = knn_idx[y * 3], j1 = knn_idx[y * 3 + 1], j2 = knn_idx[y * 3 + 2];
    float inv = 1.0f / (w0 + w1 + w2);
    float2 a = *(const float2*)&x0[j0 * 128 + i0];
    float2 b = *(const float2*)&x0[j1 * 128 + i0];
    float2 c = *(const float2*)&x0[j2 * 128 + i0];
    float2 r;
    r.x = (w0 * a.x + w1 * b.x + w2 * c.x) * inv;
    r.y = (w0 * a.y + w1 * b.y + w2 * c.y) * inv;
    *(float2*)&x1[y * 128 + i0] = r;
}

// ---------------------------------------------------------------------------
// Output head: out[y] = [x1[y] | pos1[y]] @ out_W.T + out_b. One wave per y.
// ---------------------------------------------------------------------------
__global__ __launch_bounds__(256)
void out_kernel(const float* __restrict__ x1, const float* __restrict__ pos1,
                const float* __restrict__ W, const float* __restrict__ b,
                float* __restrict__ out) {
    int wave = threadIdx.x >> 6;
    int lane = threadIdx.x & 63;
    int y = blockIdx.x * 4 + wave;
    float h0 = x1[y * 128 + lane];
    float h1 = x1[y * 128 + 64 + lane];
    float acc[3];
#pragma unroll
    for (int o = 0; o < 3; ++o) {
        float p = h0 * W[o * 131 + lane] + h1 * W[o * 131 + 64 + lane];
#pragma unroll
        for (int off = 1; off < 64; off <<= 1) p += __shfl_xor(p, off, 64);
        acc[o] = p;
    }
    if (lane == 0) {
        float p0 = pos1[y * 3], p1 = pos1[y * 3 + 1], p2 = pos1[y * 3 + 2];
#pragma unroll
        for (int o = 0; o < 3; ++o) {
            out[y * 3 + o] = acc[o] + b[o] + p0 * W[o * 131 + 128]
                           + p1 * W[o * 131 + 129] + p2 * W[o * 131 + 130];
        }
    }
}

// ---------------------------------------------------------------------------
extern "C" void kernel_launch(void* const* d_in, const int* in_sizes, int n_in,
                              void* d_out, int out_size, void* d_ws, size_t ws_size,
                              hipStream_t stream) {
    (void)in_sizes; (void)n_in; (void)out_size; (void)ws_size;
    const float* latent   = (const float*)d_in[0];
    const float* pos0     = (const float*)d_in[1];
    const float* pos1     = (const float*)d_in[2];
    const float* conv_Wl  = (const float*)d_in[5];
    const float* conv_bl  = (const float*)d_in[6];
    const float* conv_Wr  = (const float*)d_in[7];
    const float* conv_br  = (const float*)d_in[8];
    const float* conv_We  = (const float*)d_in[9];
    const float* conv_att = (const float*)d_in[10];
    const float* conv_bias= (const float*)d_in[11];
    const float* lin0_W   = (const float*)d_in[12];
    const float* lin0_b   = (const float*)d_in[13];
    const float* lins_W   = (const float*)d_in[14];
    const float* lins_b   = (const float*)d_in[15];
    const float* out_W    = (const float*)d_in[16];
    const float* out_b    = (const float*)d_in[17];
    float* out = (float*)d_out;

    char* ws = (char*)d_ws;
    unsigned short* Wswz = (unsigned short*)ws; ws += (size_t)4 * WSWZ_PER_LAYER * 2; // 655,360
    float* bias_cat = (float*)ws;  ws += (size_t)4 * JTOT * 4;
    float* Wt0      = (float*)ws;  ws += (size_t)64 * 128 * 4;
    unsigned short* hswz = (unsigned short*)ws; ws += (size_t)(N1 / 16) * NG * 64 * 8 * 2; // 5.24 MB
    float* bufA     = (float*)ws;  ws += (size_t)N1 * 128 * 4;
    float* bufB     = (float*)ws;  ws += (size_t)N1 * 128 * 4;
    float* xlb      = (float*)ws;  ws += (size_t)N1 * 128 * 4;
    float* xrb      = (float*)ws;  ws += (size_t)N1 * 128 * 4;
    float* linb     = (float*)ws;  ws += (size_t)N1 * 128 * 4;
    float* peb      = (float*)ws;  ws += (size_t)N1 * 128 * 4;
    float* pb_d     = (float*)ws;  ws += (size_t)KCH * N1 * 3 * 4;
    int*   pb_i     = (int*)ws;    ws += (size_t)KCH * N1 * 3 * 4;
    int*   knn_idx  = (int*)ws;    ws += (size_t)N1 * 3 * 4;
    float* knn_w    = (float*)ws;  ws += (size_t)N1 * 3 * 4;

    prep_kernel<<<1320, 256, 0, stream>>>(conv_Wl, conv_Wr, conv_We, lins_W,
                                          conv_bl, conv_br, lins_b, lin0_W,
                                          Wswz, bias_cat, Wt0);
    lin0_kernel<<<N0, 128, 0, stream>>>(latent, Wt0, lin0_b, bufA);

    const int NCH0 = (N0 / 16) * NG * 64;   // 81920 chunks
    const int NCH1 = (N1 / 16) * NG * 64;   // 327680 chunks

    float* cur = bufA; float* nxt = bufB;
    for (int c = 0; c < 2; ++c) {
        convert_kernel<<<(NCH0 + 255) / 256, 256, 0, stream>>>(cur, pos0, hswz, NCH0);
        gemm_mfma_kernel<<<N0 / 32, 256, 0, stream>>>(
            hswz, Wswz + (size_t)c * WSWZ_PER_LAYER, bias_cat + c * JTOT,
            xlb, xrb, linb, peb, N0);
        gat_gather_kernel<<<N0 / 4, 256, 0, stream>>>(
            xlb, xrb, peb, linb, conv_att + c * 128, conv_bias + c * 128,
            nxt, N0);
        float* t = cur; cur = nxt; nxt = t;
    }

    knn_part_kernel<<<dim3(N1 / (256 * YPT), KCH), 256, 0, stream>>>(pos0, pos1, pb_d, pb_i);
    knn_merge_kernel<<<N1 / 256, 256, 0, stream>>>(pb_d, pb_i, knn_idx, knn_w);
    interp_kernel<<<N1 / 4, 256, 0, stream>>>(cur, knn_idx, knn_w, bufB);

    cur = bufB; nxt = bufA;
    for (int c = 2; c < 4; ++c) {
        convert_kernel<<<(NCH1 + 255) / 256, 256, 0, stream>>>(cur, pos1, hswz, NCH1);
        gemm_mfma_kernel<<<N1 / 32, 256, 0, stream>>>(
            hswz, Wswz + (size_t)c * WSWZ_PER_LAYER, bias_cat + c * JTOT,
            xlb, xrb, linb, peb, N1);
        gat_gather_kernel<<<N1 / 4, 256, 0, stream>>>(
            xlb, xrb, peb, linb, conv_att + c * 128, conv_bias + c * 128,
            nxt, N1);
        float* t = cur; cur = nxt; nxt = t;
    }

    out_kernel<<<N1 / 4, 256, 0, stream>>>(cur, pos1, out_W, out_b, out);
}

// Round 8
// 292.555 us; speedup vs baseline: 3.3752x; 1.1273x over previous
//
#include <hip/hip_runtime.h>
#include <hip/hip_bf16.h>

#define N0 4096
#define N1 16384
#define HID 128
#define LAT 64
#define DIM 3
#define NAUG 21
#define JTOT 512    // xl(128) | xr(128) | lins(128) | pe(128)
#define KPAD 160    // K padded to 5 groups of 32 (131 real)
#define NT 32       // 512/16 n-tiles
#define NG 5        // k-groups per tile row

typedef __attribute__((ext_vector_type(8))) short bf16x8;
typedef __attribute__((ext_vector_type(4))) float f32x4;

__device__ __constant__ int c_aug[NAUG] = {1,2,3,4,5,6,7,8,9,10,11,12,13,14,
                                           15,16,17,18,19,21,24};

__device__ __forceinline__ unsigned short f2bf(float v) {
    __hip_bfloat16 b = __float2bfloat16(v);
    return *reinterpret_cast<unsigned short*>(&b);
}

// ---------------------------------------------------------------------------
// Prep: build Wswz[c][nt(32)][g(5)][l(64)][j(8)] bf16 B-fragments,
// bias_cat[c][512] f32, Wt0[k(64)][j(128)] f32 for lin0.
// B[k][n]: k = g*32 + (l>>4)*8 + j, n = nt*16 + (l&15).
// ---------------------------------------------------------------------------
#define WSWZ_PER_LAYER 81920   // 160*512
__global__ void prep_kernel(const float* __restrict__ Wl,
                            const float* __restrict__ Wr,
                            const float* __restrict__ We,
                            const float* __restrict__ linsW,
                            const float* __restrict__ bl,
                            const float* __restrict__ br,
                            const float* __restrict__ linsb,
                            const float* __restrict__ lin0W,
                            unsigned short* __restrict__ Wswz,
                            float* __restrict__ bias_cat,
                            float* __restrict__ Wt0) {
    int tid = blockIdx.x * blockDim.x + threadIdx.x;
    const int NSWZ = 4 * WSWZ_PER_LAYER;     // 327680
    if (tid < NSWZ) {
        int c = tid / WSWZ_PER_LAYER;
        int r = tid - c * WSWZ_PER_LAYER;    // ((nt*5+g)*64+l)*8+j
        int nt = r / 2560;
        int g  = (r / 512) % 5;
        int l  = (r / 8) % 64;
        int j  = r % 8;
        int k  = g * 32 + (l >> 4) * 8 + j;
        int n  = nt * 16 + (l & 15);
        float v = 0.0f;
        if (k < 131) {
            if (n < 128)      v = Wl[(c * 128 + n) * 131 + k];
            else if (n < 256) v = Wr[(c * 128 + (n - 128)) * 131 + k];
            else if (n < 384) v = linsW[(c * 128 + (n - 256)) * 131 + k];
            else              v = (k >= 128) ? We[(c * 128 + (n - 384)) * 3 + (k - 128)]
                                             : 0.0f;
        }
        Wswz[tid] = f2bf(v);
    } else if (tid < NSWZ + 4 * JTOT) {      // bias_cat
        int idx = tid - NSWZ;
        int c = idx / JTOT;
        int j = idx - c * JTOT;
        float v;
        if (j < 128)        v = bl[c * 128 + j];
        else if (j < 256)   v = br[c * 128 + (j - 128)];
        else if (j < 384)   v = linsb[c * 128 + (j - 256)];
        else                v = 0.0f;
        bias_cat[idx] = v;
    } else if (tid < NSWZ + 4 * JTOT + 64 * 128) {  // Wt0
        int idx = tid - NSWZ - 4 * JTOT;
        int k = idx / 128;
        int j = idx - k * 128;
        Wt0[idx] = lin0W[j * 64 + k];
    }
}

// ---------------------------------------------------------------------------
// lin0: x0[n][j] = latent[n] . lin0_W[j] + b[j]   (4096x64 @ 64x128)
// ---------------------------------------------------------------------------
__global__ void lin0_kernel(const float* __restrict__ latent,
                            const float* __restrict__ Wt0,
                            const float* __restrict__ b,
                            float* __restrict__ x0) {
    __shared__ float lrow[64];
    int n = blockIdx.x;
    int j = threadIdx.x;
    if (j < 64) lrow[j] = latent[n * 64 + j];
    __syncthreads();
    float acc = b[j];
#pragma unroll 8
    for (int k = 0; k < 64; ++k) acc += lrow[k] * Wt0[k * 128 + j];
    x0[n * 128 + j] = acc;
}

// ---------------------------------------------------------------------------
// Convert h=[x|pos|0] rows to A-fragment-swizzled bf16:
// hswz[mt][g(5)][l(64)][j(8)]: element = h[mt*16 + (l&15)][g*32 + (l>>4)*8 + j].
// ---------------------------------------------------------------------------
__global__ __launch_bounds__(256)
void convert_kernel(const float* __restrict__ x, const float* __restrict__ pos,
                    unsigned short* __restrict__ hswz, int nchunks) {
    int t = blockIdx.x * 256 + threadIdx.x;
    if (t >= nchunks) return;
    int l = t & 63;
    int g = (t >> 6) % 5;
    int mt = t / 320;
    int m = mt * 16 + (l & 15);
    int kbase = g * 32 + (l >> 4) * 8;
    unsigned short o[8];
    if (kbase + 8 <= 128) {
        const float* p = &x[m * 128 + kbase];
        float4 v0 = *(const float4*)p;
        float4 v1 = *(const float4*)(p + 4);
        o[0] = f2bf(v0.x); o[1] = f2bf(v0.y); o[2] = f2bf(v0.z); o[3] = f2bf(v0.w);
        o[4] = f2bf(v1.x); o[5] = f2bf(v1.y); o[6] = f2bf(v1.z); o[7] = f2bf(v1.w);
    } else {
#pragma unroll
        for (int j = 0; j < 8; ++j) {
            int k = kbase + j;
            float v = (k < 128) ? x[m * 128 + k]
                    : (k < 131) ? pos[m * 3 + (k - 128)] : 0.0f;
            o[j] = f2bf(v);
        }
    }
    *(bf16x8*)&hswz[t * 8] = *(bf16x8*)o;
}

// ---------------------------------------------------------------------------
// MFMA GEMM: [xl|xr|lin|pe](M x 512) = h(M x 160) @ W + bias.
// ---------------------------------------------------------------------------
__global__ __launch_bounds__(256)
void gemm_mfma_kernel(const unsigned short* __restrict__ hswz,
                      const unsigned short* __restrict__ Wswz,  // this layer
                      const float* __restrict__ bias_cat,       // this layer
                      float* __restrict__ xl, float* __restrict__ xr,
                      float* __restrict__ lin, float* __restrict__ pe,
                      int M) {
    int w = threadIdx.x >> 6;
    int l = threadIdx.x & 63;
    int quad = l >> 4, lcol = l & 15;
    int mt0 = blockIdx.x * 2;

    bf16x8 a[2][NG];
#pragma unroll
    for (int i = 0; i < 2; ++i)
#pragma unroll
        for (int g = 0; g < NG; ++g)
            a[i][g] = *(const bf16x8*)&hswz[(size_t)(((mt0 + i) * NG + g) * 64 + l) * 8];

    float* dst = (w == 0) ? xl : (w == 1) ? xr : (w == 2) ? lin : pe;

#pragma unroll
    for (int q = 0; q < 8; ++q) {
        int nt = w * 8 + q;
        bf16x8 b[NG];
#pragma unroll
        for (int g = 0; g < NG; ++g)
            b[g] = *(const bf16x8*)&Wswz[(size_t)((nt * NG + g) * 64 + l) * 8];
        float bias = bias_cat[nt * 16 + lcol];
        f32x4 c0 = {bias, bias, bias, bias};
        f32x4 c1 = {bias, bias, bias, bias};
#pragma unroll
        for (int g = 0; g < NG; ++g) {
            c0 = __builtin_amdgcn_mfma_f32_16x16x32_bf16(a[0][g], b[g], c0, 0, 0, 0);
            c1 = __builtin_amdgcn_mfma_f32_16x16x32_bf16(a[1][g], b[g], c1, 0, 0, 0);
        }
        int jj = q * 16 + lcol;
#pragma unroll
        for (int r = 0; r < 4; ++r) {
            int m0 = mt0 * 16 + quad * 4 + r;
            dst[(size_t)m0 * 128 + jj] = c0[r];
            dst[(size_t)(m0 + 16) * 128 + jj] = c1[r];
        }
    }
}

// ---------------------------------------------------------------------------
// GATv2 gather: per-lane partial dots, then batched butterfly reduction.
// ---------------------------------------------------------------------------
__global__ __launch_bounds__(256)
void gat_gather_kernel(const float* __restrict__ xl, const float* __restrict__ xr,
                       const float* __restrict__ pe, const float* __restrict__ lin,
                       const float* __restrict__ att, const float* __restrict__ bias,
                       float* __restrict__ xout, int N) {
    int wave = threadIdx.x >> 6;
    int lane = threadIdx.x & 63;
    int d = blockIdx.x * 4 + wave;
    if (d >= N) return;
    int i0 = 2 * lane;

    float att0 = att[i0], att1 = att[i0 + 1];
    float2 xld = *(const float2*)&xl[d * 128 + i0];
    float2 xrd = *(const float2*)&xr[d * 128 + i0];
    float2 ped = *(const float2*)&pe[d * 128 + i0];

    float a[NAUG + 1];
    float xs0[NAUG], xs1[NAUG];
    float pes0 = 0.0f, pes1 = 0.0f;

#pragma unroll
    for (int k = 0; k < NAUG; ++k) {
        int s = d - c_aug[k];
        if (s < 0) s += N;
        float2 xls = *(const float2*)&xl[s * 128 + i0];
        float2 pes = *(const float2*)&pe[s * 128 + i0];
        xs0[k] = xls.x; xs1[k] = xls.y;
        pes0 += pes.x;  pes1 += pes.y;
        float m0 = xls.x + xrd.x + ped.x - pes.x;
        float m1 = xls.y + xrd.y + ped.y - pes.y;
        m0 = m0 > 0.0f ? m0 : 0.2f * m0;
        m1 = m1 > 0.0f ? m1 : 0.2f * m1;
        a[k] = att0 * m0 + att1 * m1;
    }
    {   // self loop: eattr = mean over in-edges = ped - mean(pes)
        const float inv21 = 1.0f / 21.0f;
        float m0 = xld.x + xrd.x + (ped.x - pes0 * inv21);
        float m1 = xld.y + xrd.y + (ped.y - pes1 * inv21);
        m0 = m0 > 0.0f ? m0 : 0.2f * m0;
        m1 = m1 > 0.0f ? m1 : 0.2f * m1;
        a[NAUG] = att0 * m0 + att1 * m1;
    }

#pragma unroll
    for (int off = 1; off < 64; off <<= 1) {
#pragma unroll
        for (int k = 0; k <= NAUG; ++k)
            a[k] += __shfl_xor(a[k], off, 64);
    }

    float amax = a[0];
#pragma unroll
    for (int k = 1; k <= NAUG; ++k) amax = fmaxf(amax, a[k]);
    float den = 0.0f;
#pragma unroll
    for (int k = 0; k <= NAUG; ++k) { a[k] = __expf(a[k] - amax); den += a[k]; }
    float inv = 1.0f / (den + 1e-16f);

    float o0 = 0.0f, o1 = 0.0f;
#pragma unroll
    for (int k = 0; k < NAUG; ++k) {
        float al = a[k] * inv;
        o0 += al * xs0[k];
        o1 += al * xs1[k];
    }
    {
        float al = a[NAUG] * inv;
        o0 += al * xld.x;
        o1 += al * xld.y;
    }
    o0 += bias[i0];
    o1 += bias[i0 + 1];
    o0 = o0 > 0.0f ? o0 : __expf(o0) - 1.0f;
    o1 = o1 > 0.0f ? o1 : __expf(o1) - 1.0f;
    float2 l2 = *(const float2*)&lin[d * 128 + i0];
    float2 res;
    res.x = o0 + l2.x;
    res.y = o1 + l2.y;
    *(float2*)&xout[d * 128 + i0] = res;
}

// ---------------------------------------------------------------------------
// knn v4: branchless top-3 with EXACT f32 distances; indices carried via
// cndmask selects (R7's key-packing quantized comparisons -> wrong neighbor
// selection).  Per pair: 3 fma + 3 cmp + min/med3/med3 + 5 select, uniform.
// ---------------------------------------------------------------------------
#define KCH 64
#define KCS 64    // 4096 / 64
#define YPT 4

__global__ __launch_bounds__(256)
void knn_part_kernel(const float* __restrict__ pos0, const float* __restrict__ pos1,
                     float* __restrict__ pb_d, int* __restrict__ pb_i) {
    __shared__ float4 sx[KCS];   // (x, y, z, |x|^2)
    int tid = threadIdx.x;
    int chunk = blockIdx.y;
    if (tid < KCS) {
        const float* p = &pos0[(chunk * KCS + tid) * 3];
        float x = p[0], y = p[1], z = p[2];
        sx[tid] = make_float4(x, y, z, x * x + y * y + z * z);
    }
    __syncthreads();
    int ybase = blockIdx.x * (256 * YPT) + tid;
    float m2y[YPT][3], sy[YPT];
#pragma unroll
    for (int u = 0; u < YPT; ++u) {
        int y = ybase + u * 256;
        float p0 = pos1[y * 3], p1 = pos1[y * 3 + 1], p2 = pos1[y * 3 + 2];
        m2y[u][0] = -2.0f * p0; m2y[u][1] = -2.0f * p1; m2y[u][2] = -2.0f * p2;
        sy[u] = p0 * p0 + p1 * p1 + p2 * p2;
    }
    float bd0[YPT], bd1[YPT], bd2[YPT];
    int   bi0[YPT], bi1[YPT], bi2[YPT];
#pragma unroll
    for (int u = 0; u < YPT; ++u) {
        bd0[u] = 1e30f; bd1[u] = 1e30f; bd2[u] = 1e30f;
        bi0[u] = 0; bi1[u] = 0; bi2[u] = 0;
    }

    int gbase = chunk * KCS;
#pragma unroll 4
    for (int i = 0; i < KCS; i += 4) {
        float4 s[4];
#pragma unroll
        for (int v = 0; v < 4; ++v) s[v] = sx[i + v];
#pragma unroll
        for (int v = 0; v < 4; ++v) {
            int gi = gbase + i + v;
#pragma unroll
            for (int u = 0; u < YPT; ++u) {
                float t = fmaf(m2y[u][0], s[v].x, s[v].w);
                t = fmaf(m2y[u][1], s[v].y, t);
                t = fmaf(m2y[u][2], s[v].z, t);
                t += sy[u];
                bool c0 = t < bd0[u];
                bool c1 = t < bd1[u];
                bool c2 = t < bd2[u];
                float n0 = fminf(bd0[u], t);
                float n1 = __builtin_amdgcn_fmed3f(bd0[u], bd1[u], t);
                float n2 = __builtin_amdgcn_fmed3f(bd1[u], bd2[u], t);
                int j0 = c0 ? gi : bi0[u];
                int j1 = c0 ? bi0[u] : (c1 ? gi : bi1[u]);
                int j2 = c1 ? bi1[u] : (c2 ? gi : bi2[u]);
                bd0[u] = n0; bd1[u] = n1; bd2[u] = n2;
                bi0[u] = j0; bi1[u] = j1; bi2[u] = j2;
            }
        }
    }
#pragma unroll
    for (int u = 0; u < YPT; ++u) {
        int y = ybase + u * 256;
        int base = (chunk * N1 + y) * 3;
        pb_d[base] = bd0[u]; pb_d[base + 1] = bd1[u]; pb_d[base + 2] = bd2[u];
        pb_i[base] = bi0[u]; pb_i[base + 1] = bi1[u]; pb_i[base + 2] = bi2[u];
    }
}

__global__ __launch_bounds__(256)
void knn_merge_kernel(const float* __restrict__ pb_d, const int* __restrict__ pb_i,
                      int* __restrict__ knn_idx, float* __restrict__ knn_w) {
    int y = blockIdx.x * 256 + threadIdx.x;
    float bd0 = 1e30f, bd1 = 1e30f, bd2 = 1e30f;
    int bi0 = 0, bi1 = 0, bi2 = 0;
    for (int c = 0; c < KCH; ++c) {
        int base = (c * N1 + y) * 3;
#pragma unroll
        for (int t3 = 0; t3 < 3; ++t3) {
            float t = pb_d[base + t3];
            int gi = pb_i[base + t3];
            bool c0 = t < bd0;
            bool c1 = t < bd1;
            bool c2 = t < bd2;
            float n0 = fminf(bd0, t);
            float n1 = __builtin_amdgcn_fmed3f(bd0, bd1, t);
            float n2 = __builtin_amdgcn_fmed3f(bd1, bd2, t);
            int j0 = c0 ? gi : bi0;
            int j1 = c0 ? bi0 : (c1 ? gi : bi1);
            int j2 = c1 ? bi1 : (c2 ? gi : bi2);
            bd0 = n0; bd1 = n1; bd2 = n2;
            bi0 = j0; bi1 = j1; bi2 = j2;
        }
    }
    knn_idx[y * 3]     = bi0;
    knn_idx[y * 3 + 1] = bi1;
    knn_idx[y * 3 + 2] = bi2;
    knn_w[y * 3]     = 1.0f / fmaxf(bd0, 1e-16f);
    knn_w[y * 3 + 1] = 1.0f / fmaxf(bd1, 1e-16f);
    knn_w[y * 3 + 2] = 1.0f / fmaxf(bd2, 1e-16f);
}

__global__ __launch_bounds__(256)
void interp_kernel(const float* __restrict__ x0, const int* __restrict__ knn_idx,
                   const float* __restrict__ knn_w, float* __restrict__ x1) {
    int wave = threadIdx.x >> 6;
    int lane = threadIdx.x & 63;
    int y = blockIdx.x * 4 + wave;
    int i0 = 2 * lane;
    float w0 = knn_w[y * 3], w1 = knn_w[y * 3 + 1], w2 = knn_w[y * 3 + 2];
    int j0 = knn_idx[y * 3], j1 = knn_idx[y * 3 + 1], j2 = knn_idx[y * 3 + 2];
    float inv = 1.0f / (w0 + w1 + w2);
    float2 a = *(const float2*)&x0[j0 * 128 + i0];
    float2 b = *(const float2*)&x0[j1 * 128 + i0];
    float2 c = *(const float2*)&x0[j2 * 128 + i0];
    float2 r;
    r.x = (w0 * a.x + w1 * b.x + w2 * c.x) * inv;
    r.y = (w0 * a.y + w1 * b.y + w2 * c.y) * inv;
    *(float2*)&x1[y * 128 + i0] = r;
}

// ---------------------------------------------------------------------------
// Output head: out[y] = [x1[y] | pos1[y]] @ out_W.T + out_b. One wave per y.
// ---------------------------------------------------------------------------
__global__ __launch_bounds__(256)
void out_kernel(const float* __restrict__ x1, const float* __restrict__ pos1,
                const float* __restrict__ W, const float* __restrict__ b,
                float* __restrict__ out) {
    int wave = threadIdx.x >> 6;
    int lane = threadIdx.x & 63;
    int y = blockIdx.x * 4 + wave;
    float h0 = x1[y * 128 + lane];
    float h1 = x1[y * 128 + 64 + lane];
    float acc[3];
#pragma unroll
    for (int o = 0; o < 3; ++o) {
        float p = h0 * W[o * 131 + lane] + h1 * W[o * 131 + 64 + lane];
#pragma unroll
        for (int off = 1; off < 64; off <<= 1) p += __shfl_xor(p, off, 64);
        acc[o] = p;
    }
    if (lane == 0) {
        float p0 = pos1[y * 3], p1 = pos1[y * 3 + 1], p2 = pos1[y * 3 + 2];
#pragma unroll
        for (int o = 0; o < 3; ++o) {
            out[y * 3 + o] = acc[o] + b[o] + p0 * W[o * 131 + 128]
                           + p1 * W[o * 131 + 129] + p2 * W[o * 131 + 130];
        }
    }
}

// ---------------------------------------------------------------------------
extern "C" void kernel_launch(void* const* d_in, const int* in_sizes, int n_in,
                              void* d_out, int out_size, void* d_ws, size_t ws_size,
                              hipStream_t stream) {
    (void)in_sizes; (void)n_in; (void)out_size; (void)ws_size;
    const float* latent   = (const float*)d_in[0];
    const float* pos0     = (const float*)d_in[1];
    const float* pos1     = (const float*)d_in[2];
    const float* conv_Wl  = (const float*)d_in[5];
    const float* conv_bl  = (const float*)d_in[6];
    const float* conv_Wr  = (const float*)d_in[7];
    const float* conv_br  = (const float*)d_in[8];
    const float* conv_We  = (const float*)d_in[9];
    const float* conv_att = (const float*)d_in[10];
    const float* conv_bias= (const float*)d_in[11];
    const float* lin0_W   = (const float*)d_in[12];
    const float* lin0_b   = (const float*)d_in[13];
    const float* lins_W   = (const float*)d_in[14];
    const float* lins_b   = (const float*)d_in[15];
    const float* out_W    = (const float*)d_in[16];
    const float* out_b    = (const float*)d_in[17];
    float* out = (float*)d_out;

    char* ws = (char*)d_ws;
    unsigned short* Wswz = (unsigned short*)ws; ws += (size_t)4 * WSWZ_PER_LAYER * 2;
    float* bias_cat = (float*)ws;  ws += (size_t)4 * JTOT * 4;
    float* Wt0      = (float*)ws;  ws += (size_t)64 * 128 * 4;
    unsigned short* hswz = (unsigned short*)ws; ws += (size_t)(N1 / 16) * NG * 64 * 8 * 2;
    float* bufA     = (float*)ws;  ws += (size_t)N1 * 128 * 4;
    float* bufB     = (float*)ws;  ws += (size_t)N1 * 128 * 4;
    float* xlb      = (float*)ws;  ws += (size_t)N1 * 128 * 4;
    float* xrb      = (float*)ws;  ws += (size_t)N1 * 128 * 4;
    float* linb     = (float*)ws;  ws += (size_t)N1 * 128 * 4;
    float* peb      = (float*)ws;  ws += (size_t)N1 * 128 * 4;
    float* pb_d     = (float*)ws;  ws += (size_t)KCH * N1 * 3 * 4;     // 12.6 MB
    int*   pb_i     = (int*)ws;    ws += (size_t)KCH * N1 * 3 * 4;     // 12.6 MB
    int*   knn_idx  = (int*)ws;    ws += (size_t)N1 * 3 * 4;
    float* knn_w    = (float*)ws;  ws += (size_t)N1 * 3 * 4;

    prep_kernel<<<1320, 256, 0, stream>>>(conv_Wl, conv_Wr, conv_We, lins_W,
                                          conv_bl, conv_br, lins_b, lin0_W,
                                          Wswz, bias_cat, Wt0);
    lin0_kernel<<<N0, 128, 0, stream>>>(latent, Wt0, lin0_b, bufA);

    const int NCH0 = (N0 / 16) * NG * 64;   // 81920 chunks
    const int NCH1 = (N1 / 16) * NG * 64;   // 327680 chunks

    float* cur = bufA; float* nxt = bufB;
    for (int c = 0; c < 2; ++c) {
        convert_kernel<<<(NCH0 + 255) / 256, 256, 0, stream>>>(cur, pos0, hswz, NCH0);
        gemm_mfma_kernel<<<N0 / 32, 256, 0, stream>>>(
            hswz, Wswz + (size_t)c * WSWZ_PER_LAYER, bias_cat + c * JTOT,
            xlb, xrb, linb, peb, N0);
        gat_gather_kernel<<<N0 / 4, 256, 0, stream>>>(
            xlb, xrb, peb, linb, conv_att + c * 128, conv_bias + c * 128,
            nxt, N0);
        float* t = cur; cur = nxt; nxt = t;
    }

    knn_part_kernel<<<dim3(N1 / (256 * YPT), KCH), 256, 0, stream>>>(pos0, pos1, pb_d, pb_i);
    knn_merge_kernel<<<N1 / 256, 256, 0, stream>>>(pb_d, pb_i, knn_idx, knn_w);
    interp_kernel<<<N1 / 4, 256, 0, stream>>>(cur, knn_idx, knn_w, bufB);

    cur = bufB; nxt = bufA;
    for (int c = 2; c < 4; ++c) {
        convert_kernel<<<(NCH1 + 255) / 256, 256, 0, stream>>>(cur, pos1, hswz, NCH1);
        gemm_mfma_kernel<<<N1 / 32, 256, 0, stream>>>(
            hswz, Wswz + (size_t)c * WSWZ_PER_LAYER, bias_cat + c * JTOT,
            xlb, xrb, linb, peb, N1);
        gat_gather_kernel<<<N1 / 4, 256, 0, stream>>>(
            xlb, xrb, peb, linb, conv_att + c * 128, conv_bias + c * 128,
            nxt, N1);
        float* t = cur; cur = nxt; nxt = t;
    }

    out_kernel<<<N1 / 4, 256, 0, stream>>>(cur, pos1, out_W, out_b, out);
}